// Round 6
// baseline (187.281 us; speedup 1.0000x reference)
//
#include <hip/hip_runtime.h>
#include <math.h>

#define NN 1024
#define BB 2
#define D 64
#define NHEAD 4
#define PH 16
#define LOG2E 1.4426950408889634f

template <int CTRL>
__device__ __forceinline__ float dpp_mov(float x) {
    int xi = __builtin_bit_cast(int, x);
    int r = __builtin_amdgcn_update_dpp(0, xi, CTRL, 0xF, 0xF, true);
    return __builtin_bit_cast(float, r);
}

// 16-lane row sum; valid in lane 15 of each row of 16.
__device__ __forceinline__ float dpp_rowsum16(float t) {
    t += dpp_mov<0x111>(t);
    t += dpp_mov<0x112>(t);
    t += dpp_mov<0x114>(t);
    t += dpp_mov<0x118>(t);
    return t;
}

// sum across a 4-lane quad via quad_perm butterfly; valid in ALL quad lanes.
__device__ __forceinline__ float quad_sum4(float t) {
    t += dpp_mov<0xB1>(t);   // quad_perm [1,0,3,2]
    t += dpp_mov<0x4E>(t);   // quad_perm [2,3,0,1]
    return t;
}

// --- Kernel 1: adjacency mask as tiled GEMM on RAW embedding rows --------
// norms are positive & finite, so (ne_i.ne_j != 0) <=> (emb_i.emb_j != 0).
#define MST 65
__global__ __launch_bounds__(256) void k_mask(const float* __restrict__ emb,
                                              unsigned char* __restrict__ mask) {
    __shared__ float As[64 * MST];
    __shared__ float Bs[64 * MST];
    int tid = threadIdx.x;
    int ib = (blockIdx.x & 15) << 6;
    int jb = (blockIdx.x >> 4) << 6;

    #pragma unroll
    for (int r = 0; r < 4; ++r) {
        int q = tid + (r << 8);
        int row = q >> 4, c4 = (q & 15) << 2;
        float4 a = *(const float4*)&emb[(ib + row) * D + c4];
        float4 b = *(const float4*)&emb[(jb + row) * D + c4];
        As[row * MST + c4 + 0] = a.x; As[row * MST + c4 + 1] = a.y;
        As[row * MST + c4 + 2] = a.z; As[row * MST + c4 + 3] = a.w;
        Bs[row * MST + c4 + 0] = b.x; Bs[row * MST + c4 + 1] = b.y;
        Bs[row * MST + c4 + 2] = b.z; Bs[row * MST + c4 + 3] = b.w;
    }
    __syncthreads();

    int i0 = (tid >> 4) << 2;
    int j0 = (tid & 15) << 2;
    float acc[4][4] = {};
    #pragma unroll 8
    for (int k = 0; k < 64; ++k) {
        float a0 = As[(i0 + 0) * MST + k];
        float a1 = As[(i0 + 1) * MST + k];
        float a2 = As[(i0 + 2) * MST + k];
        float a3 = As[(i0 + 3) * MST + k];
        float b0 = Bs[(j0 + 0) * MST + k];
        float b1 = Bs[(j0 + 1) * MST + k];
        float b2 = Bs[(j0 + 2) * MST + k];
        float b3 = Bs[(j0 + 3) * MST + k];
        acc[0][0] = fmaf(a0, b0, acc[0][0]); acc[0][1] = fmaf(a0, b1, acc[0][1]);
        acc[0][2] = fmaf(a0, b2, acc[0][2]); acc[0][3] = fmaf(a0, b3, acc[0][3]);
        acc[1][0] = fmaf(a1, b0, acc[1][0]); acc[1][1] = fmaf(a1, b1, acc[1][1]);
        acc[1][2] = fmaf(a1, b2, acc[1][2]); acc[1][3] = fmaf(a1, b3, acc[1][3]);
        acc[2][0] = fmaf(a2, b0, acc[2][0]); acc[2][1] = fmaf(a2, b1, acc[2][1]);
        acc[2][2] = fmaf(a2, b2, acc[2][2]); acc[2][3] = fmaf(a2, b3, acc[2][3]);
        acc[3][0] = fmaf(a3, b0, acc[3][0]); acc[3][1] = fmaf(a3, b1, acc[3][1]);
        acc[3][2] = fmaf(a3, b2, acc[3][2]); acc[3][3] = fmaf(a3, b3, acc[3][3]);
    }
    #pragma unroll
    for (int r = 0; r < 4; ++r) {
        int gi = ib + i0 + r;
        uchar4 m;
        m.x = (acc[r][0] != 0.f || gi == jb + j0 + 0) ? 1 : 0;
        m.y = (acc[r][1] != 0.f || gi == jb + j0 + 1) ? 1 : 0;
        m.z = (acc[r][2] != 0.f || gi == jb + j0 + 2) ? 1 : 0;
        m.w = (acc[r][3] != 0.f || gi == jb + j0 + 3) ? 1 : 0;
        *(uchar4*)&mask[gi * NN + jb + j0] = m;
    }
}

// --- Kernel 2: dual GEMM + alE tail --------------------------------------
// xl = A@Wl, xr = A@Wr; alE[r][h] = 0.6*log2(e)*sum_p att[h,p]*xl[r,h,p]
__global__ __launch_bounds__(256) void k_gemm2(const float* __restrict__ A,
                                               const float* __restrict__ Wl,
                                               const float* __restrict__ Wr,
                                               const float* __restrict__ att,
                                               float* __restrict__ xl,
                                               float* __restrict__ xr,
                                               float* __restrict__ alE) {
    __shared__ float wl[64 * 64];
    __shared__ float wr[64 * 64];
    int tid = threadIdx.x;
    for (int t = tid; t < 4096; t += 256) { wl[t] = Wl[t]; wr[t] = Wr[t]; }
    __syncthreads();
    int r = blockIdx.x * 4 + (tid >> 6);
    int c = tid & 63;
    float av = att[c];
    const float* arow = A + r * 64;
    float accl = 0.f, accr = 0.f;
    #pragma unroll
    for (int p = 0; p < 64; ++p) {
        float a = arow[p];
        accl = fmaf(a, wl[p * 64 + c], accl);
        accr = fmaf(a, wr[p * 64 + c], accr);
    }
    xl[r * 64 + c] = accl;
    xr[r * 64 + c] = accr;
    float t = dpp_rowsum16(accl * av);
    if ((c & 15) == 15) alE[(r << 2) | (c >> 4)] = 0.6f * LOG2E * t;
}

// --- Kernel 3: fused flash GATv2, TI=1, one block per (b, i) -------------
// lane = 4*jl + h; quad (jl) shares row j = wave*256 + jl*16 + s.
// Lane's xv slot (q,r) = feature f = q*16 + 4h + r (head q, pos 4h+r).
// e'[j,q] = quadsum(sum_r at'*|xr+xv|) + arE[q] + alE[j][q],
// at' = 0.4*log2e*att, arE = 1.5*quadsum(at'.xr). pe = exp2(e') (bounded).
template <bool RELU>
__global__ __launch_bounds__(256, 6) void k_attn(
    const float* __restrict__ xl, const float* __restrict__ xr,
    const float* __restrict__ att, const float* __restrict__ alE,
    const float* __restrict__ bias, const unsigned char* __restrict__ mask,
    float* __restrict__ out)
{
    __shared__ float Opart[4][4][64];   // [wave][jlgrp][f]
    __shared__ float Lpart[4][4][NHEAD];

    int tid = threadIdx.x;
    int wave = tid >> 6, lane = tid & 63;
    int h = lane & 3, jl = lane >> 2;
    int b = blockIdx.x >> 10;
    int i = blockIdx.x & 1023;
    int j0 = (wave << 8) + (jl << 4);

    const float* xlb = xl + (b << 16);

    // persistent fragments: slot q*4+r <-> feature q*16+4h+r
    float at[16], xrf[16];
    {
        const float* ap = att + (h << 2);
        const float* r0 = xr + (((b << 10) + i) << 6) + (h << 2);
        #pragma unroll
        for (int q = 0; q < 4; ++q) {
            *(float4*)&at[q << 2]  = *(const float4*)(ap + (q << 4));
            *(float4*)&xrf[q << 2] = *(const float4*)(r0 + (q << 4));
        }
        #pragma unroll
        for (int p = 0; p < 16; ++p) at[p] *= 0.4f * LOG2E;
    }
    float arq[4];
    #pragma unroll
    for (int q = 0; q < 4; ++q) {
        float p0 = 0.f;
        #pragma unroll
        for (int r = 0; r < 4; ++r)
            p0 = fmaf(at[(q << 2) + r], xrf[(q << 2) + r], p0);
        arq[q] = 1.5f * quad_sum4(p0);
    }

    // pack this lane's 16 mask bytes into 16 bits
    unsigned mb = 0;
    {
        const unsigned* mp = (const unsigned*)(mask + i * NN + j0);
        #pragma unroll
        for (int q = 0; q < 4; ++q) {
            unsigned w = mp[q];
            mb |= ((((w >> 0) & 1) | ((w >> 7) & 2) | ((w >> 14) & 4) | ((w >> 21) & 8)) << (q << 2));
        }
    }

    float O[16], lq[4] = {};
    #pragma unroll
    for (int p = 0; p < 16; ++p) O[p] = 0.f;

    const float* xrow = xlb + (j0 << 6) + (h << 2);
    const float* alp  = alE + (b << 12) + (j0 << 2);

    for (int s = 0; s < 16; ++s) {
        const float* rp = xrow + (s << 6);
        float xv[16];
        *(float4*)&xv[0]  = *(const float4*)(rp);
        *(float4*)&xv[4]  = *(const float4*)(rp + 16);
        *(float4*)&xv[8]  = *(const float4*)(rp + 32);
        *(float4*)&xv[12] = *(const float4*)(rp + 48);
        float alr[4];
        *(float4*)alr = *(const float4*)(alp + (s << 2));
        bool m = (mb >> s) & 1;

        #pragma unroll
        for (int q = 0; q < 4; ++q) {
            float p0 = 0.f;
            #pragma unroll
            for (int r = 0; r < 4; ++r)
                p0 = fmaf(at[(q << 2) + r],
                          __builtin_fabsf(xrf[(q << 2) + r] + xv[(q << 2) + r]), p0);
            float e = quad_sum4(p0) + (arq[q] + alr[q]);
            float pe = m ? __builtin_amdgcn_exp2f(e) : 0.f;
            lq[q] += pe;
            #pragma unroll
            for (int r = 0; r < 4; ++r)
                O[(q << 2) + r] = fmaf(pe, xv[(q << 2) + r], O[(q << 2) + r]);
        }
    }

    // reduce over the 4 jl's within each 16-lane DPP row (strides 4, 8)
    #pragma unroll
    for (int p = 0; p < 16; ++p) {
        O[p] += dpp_mov<0x114>(O[p]);
        O[p] += dpp_mov<0x118>(O[p]);
    }
    #pragma unroll
    for (int q = 0; q < 4; ++q) {
        lq[q] += dpp_mov<0x114>(lq[q]);
        lq[q] += dpp_mov<0x118>(lq[q]);
    }

    if ((lane & 15) >= 12) {             // lanes 12..15 of each 16-row
        int k = lane >> 4;               // jl group
        #pragma unroll
        for (int q = 0; q < 4; ++q)
            *(float4*)&Opart[wave][k][(q << 4) + (h << 2)] = *(const float4*)&O[q << 2];
        if (h == 0) {
            #pragma unroll
            for (int q = 0; q < 4; ++q) Lpart[wave][k][q] = lq[q];
        }
    }
    __syncthreads();

    if (tid < 64) {
        float o = 0.f, l = 0.f;
        #pragma unroll
        for (int w = 0; w < 4; ++w)
            #pragma unroll
            for (int k = 0; k < 4; ++k) {
                o += Opart[w][k][tid];
                l += Lpart[w][k][tid >> 4];
            }
        float res = o / l + bias[tid];
        if (RELU) res = fmaxf(res, 0.f);
        out[(((b << 10) + i) << 6) + tid] = res;
    }
}

extern "C" void kernel_launch(void* const* d_in, const int* in_sizes, int n_in,
                              void* d_out, int out_size, void* d_ws, size_t ws_size,
                              hipStream_t stream) {
    const float* x    = (const float*)d_in[0];
    const float* emb  = (const float*)d_in[1];
    const float* Wl1  = (const float*)d_in[2];
    const float* Wr1  = (const float*)d_in[3];
    const float* att1 = (const float*)d_in[4];
    const float* b1   = (const float*)d_in[5];
    const float* Wl2  = (const float*)d_in[6];
    const float* Wr2  = (const float*)d_in[7];
    const float* att2 = (const float*)d_in[8];
    const float* b2   = (const float*)d_in[9];
    float* out = (float*)d_out;

    unsigned char* mask = (unsigned char*)d_ws;                 // 1MB
    float* xl = (float*)(mask + NN * NN);                       // 512KB
    float* xr = xl + BB * NN * D;                               // 512KB
    float* hbuf = xr + BB * NN * D;                             // 512KB
    float* alE = hbuf + BB * NN * D;                            // 32KB

    k_mask<<<256, 256, 0, stream>>>(emb, mask);

    k_gemm2<<<BB * NN / 4, 256, 0, stream>>>(x, Wl1, Wr1, att1, xl, xr, alE);
    k_attn<true><<<BB * NN, 256, 0, stream>>>(xl, xr, att1, alE, b1, mask, hbuf);

    k_gemm2<<<BB * NN / 4, 256, 0, stream>>>(hbuf, Wl2, Wr2, att2, xl, xr, alE);
    k_attn<false><<<BB * NN, 256, 0, stream>>>(xl, xr, att2, alE, b2, mask, out);
}

// Round 9
// 149.223 us; speedup vs baseline: 1.2550x; 1.2550x over previous
//
#include <hip/hip_runtime.h>
#include <math.h>

#define NN 1024
#define LOG2E 1.4426950408889634f

template <int CTRL>
__device__ __forceinline__ float dpp_mov(float x) {
    int xi = __builtin_bit_cast(int, x);
    int r = __builtin_amdgcn_update_dpp(0, xi, CTRL, 0xF, 0xF, true);
    return __builtin_bit_cast(float, r);
}
__device__ __forceinline__ float dpp_rowsum16(float t) {
    t += dpp_mov<0x111>(t);
    t += dpp_mov<0x112>(t);
    t += dpp_mov<0x114>(t);
    t += dpp_mov<0x118>(t);
    return t;
}
__device__ __forceinline__ float quad_sum4(float t) {
    t += dpp_mov<0xB1>(t);   // quad_perm [1,0,3,2]
    t += dpp_mov<0x4E>(t);   // quad_perm [2,3,0,1]
    return t;
}

// --- one 32(i) x 16(j) adjacency tile per task ----------------------------
// (emb_i.emb_j != 0) <=> (ne_i.ne_j != 0) since norms are positive finite.
__device__ void mask_tile(const float* __restrict__ emb,
                          unsigned char* __restrict__ mask, int task, float* sm) {
    float* As = sm;             // 32*65
    float* Bs = sm + 32 * 65;   // 16*65
    int tid = threadIdx.x;
    int ib = (task & 31) << 5;
    int jb = (task >> 5) << 4;
    #pragma unroll
    for (int r = 0; r < 2; ++r) {
        int q = tid + (r << 8);
        int row = q >> 4, c4 = (q & 15) << 2;
        float4 a = *(const float4*)&emb[(ib + row) * 64 + c4];
        As[row * 65 + c4 + 0] = a.x; As[row * 65 + c4 + 1] = a.y;
        As[row * 65 + c4 + 2] = a.z; As[row * 65 + c4 + 3] = a.w;
    }
    {
        int row = tid >> 4, c4 = (tid & 15) << 2;
        float4 b = *(const float4*)&emb[(jb + row) * 64 + c4];
        Bs[row * 65 + c4 + 0] = b.x; Bs[row * 65 + c4 + 1] = b.y;
        Bs[row * 65 + c4 + 2] = b.z; Bs[row * 65 + c4 + 3] = b.w;
    }
    __syncthreads();
    int i1 = tid >> 4, j = tid & 15;
    float acc1 = 0.f, acc2 = 0.f;
    #pragma unroll 8
    for (int k = 0; k < 64; ++k) {
        float bv = Bs[j * 65 + k];
        acc1 = fmaf(As[i1 * 65 + k], bv, acc1);
        acc2 = fmaf(As[(i1 + 16) * 65 + k], bv, acc2);
    }
    int gi1 = ib + i1, gi2 = ib + i1 + 16, gj = jb + j;
    mask[gi1 * NN + gj] = (acc1 != 0.f || gi1 == gj) ? 1 : 0;
    mask[gi2 * NN + gj] = (acc2 != 0.f || gi2 == gj) ? 1 : 0;
}

// --- GEMM row r from LDS hrow (first 64 threads) + alE tail ---------------
__device__ void gemm_row(const float* __restrict__ Wl, const float* __restrict__ Wr,
                         const float* __restrict__ att, const float* hrow,
                         float* __restrict__ xl, float* __restrict__ xr,
                         float* __restrict__ alE, int r) {
    int tid = threadIdx.x;
    if (tid < 64) {
        int c = tid;
        float accl = 0.f, accr = 0.f;
        #pragma unroll 8
        for (int p = 0; p < 64; ++p) {
            float a = hrow[p];
            accl = fmaf(a, Wl[p * 64 + c], accl);
            accr = fmaf(a, Wr[p * 64 + c], accr);
        }
        xl[r * 64 + c] = accl;
        xr[r * 64 + c] = accr;
        float t = dpp_rowsum16(accl * att[c]);
        if ((c & 15) == 15) alE[(r << 2) | (c >> 4)] = 0.6f * LOG2E * t;
    }
}

// --- Attention partial: TI=2 rows, half of j (js), quad-cooperative -------
// task = (ipair << 1) | js; lane = 4*jl + h; quad shares row
// j = js*512 + wave*128 + jl*8 + s.  e' = quadsum(sum at'|xr+xv|)+arE+alE[j].
__device__ void attn_partial(const float* __restrict__ xl, const float* __restrict__ xr,
                             const float* __restrict__ att, const float* __restrict__ alE,
                             const unsigned char* __restrict__ mask,
                             float* __restrict__ Opar, float* __restrict__ lpar,
                             int task, float* sm) {
    float* sO = sm;          // [ii][16 wk][64]  = 2048 floats
    float* sL = sm + 2048;   // [ii][16 wk][4 q] = 128 floats
    int tid = threadIdx.x;
    int wave = tid >> 6, lane = tid & 63;
    int h = lane & 3, jl = lane >> 2;
    int js = task & 1;
    int p  = task >> 1;            // ipair
    int b  = p >> 9;
    int i0 = (p & 511) << 1;
    int jbase = (js << 9) + (wave << 7) + (jl << 3);

    const float* xlb = xl + (b << 16);
    float at[16], xr0f[16], xr1f[16];
    {
        const float* ap = att + (h << 2);
        const float* r0 = xr + (((b << 10) + i0) << 6) + (h << 2);
        const float* r1 = r0 + 64;
        #pragma unroll
        for (int q = 0; q < 4; ++q) {
            *(float4*)&at[q << 2]   = *(const float4*)(ap + (q << 4));
            *(float4*)&xr0f[q << 2] = *(const float4*)(r0 + (q << 4));
            *(float4*)&xr1f[q << 2] = *(const float4*)(r1 + (q << 4));
        }
        #pragma unroll
        for (int pp = 0; pp < 16; ++pp) at[pp] *= 0.4f * LOG2E;
    }
    float ar0q[4], ar1q[4];
    #pragma unroll
    for (int q = 0; q < 4; ++q) {
        float p0 = 0.f, p1 = 0.f;
        #pragma unroll
        for (int rr = 0; rr < 4; ++rr) {
            p0 = fmaf(at[(q << 2) + rr], xr0f[(q << 2) + rr], p0);
            p1 = fmaf(at[(q << 2) + rr], xr1f[(q << 2) + rr], p1);
        }
        ar0q[q] = 1.5f * quad_sum4(p0);
        ar1q[q] = 1.5f * quad_sum4(p1);
    }
    unsigned mb0 = 0, mb1 = 0;
    {
        const unsigned* m0p = (const unsigned*)(mask + i0 * NN + jbase);
        const unsigned* m1p = (const unsigned*)(mask + (i0 + 1) * NN + jbase);
        #pragma unroll
        for (int q = 0; q < 2; ++q) {
            unsigned w0 = m0p[q], w1 = m1p[q];
            mb0 |= ((((w0 >> 0) & 1) | ((w0 >> 7) & 2) | ((w0 >> 14) & 4) | ((w0 >> 21) & 8)) << (q << 2));
            mb1 |= ((((w1 >> 0) & 1) | ((w1 >> 7) & 2) | ((w1 >> 14) & 4) | ((w1 >> 21) & 8)) << (q << 2));
        }
    }
    float O0[16], O1[16], l0q[4] = {0,0,0,0}, l1q[4] = {0,0,0,0};
    #pragma unroll
    for (int pp = 0; pp < 16; ++pp) { O0[pp] = 0.f; O1[pp] = 0.f; }
    const float* xrow = xlb + (jbase << 6) + (h << 2);
    const float* alp  = alE + (b << 12) + (jbase << 2);
    #pragma unroll 2
    for (int s = 0; s < 8; ++s) {
        const float* rp = xrow + (s << 6);
        float xv[16];
        *(float4*)&xv[0]  = *(const float4*)(rp);
        *(float4*)&xv[4]  = *(const float4*)(rp + 16);
        *(float4*)&xv[8]  = *(const float4*)(rp + 32);
        *(float4*)&xv[12] = *(const float4*)(rp + 48);
        float alr[4];
        *(float4*)alr = *(const float4*)(alp + (s << 2));
        bool m0 = (mb0 >> s) & 1, m1 = (mb1 >> s) & 1;
        #pragma unroll
        for (int q = 0; q < 4; ++q) {
            float p0 = 0.f, p1 = 0.f;
            #pragma unroll
            for (int rr = 0; rr < 4; ++rr) {
                float xvv = xv[(q << 2) + rr];
                float a = at[(q << 2) + rr];
                p0 = fmaf(a, __builtin_fabsf(xr0f[(q << 2) + rr] + xvv), p0);
                p1 = fmaf(a, __builtin_fabsf(xr1f[(q << 2) + rr] + xvv), p1);
            }
            float e0 = quad_sum4(p0) + (ar0q[q] + alr[q]);
            float e1 = quad_sum4(p1) + (ar1q[q] + alr[q]);
            float pe0 = m0 ? __builtin_amdgcn_exp2f(e0) : 0.f;
            float pe1 = m1 ? __builtin_amdgcn_exp2f(e1) : 0.f;
            l0q[q] += pe0; l1q[q] += pe1;
            #pragma unroll
            for (int rr = 0; rr < 4; ++rr) {
                float xvv = xv[(q << 2) + rr];
                O0[(q << 2) + rr] = fmaf(pe0, xvv, O0[(q << 2) + rr]);
                O1[(q << 2) + rr] = fmaf(pe1, xvv, O1[(q << 2) + rr]);
            }
        }
    }
    #pragma unroll
    for (int pp = 0; pp < 16; ++pp) {
        O0[pp] += dpp_mov<0x114>(O0[pp]); O0[pp] += dpp_mov<0x118>(O0[pp]);
        O1[pp] += dpp_mov<0x114>(O1[pp]); O1[pp] += dpp_mov<0x118>(O1[pp]);
    }
    #pragma unroll
    for (int q = 0; q < 4; ++q) {
        l0q[q] += dpp_mov<0x114>(l0q[q]); l0q[q] += dpp_mov<0x118>(l0q[q]);
        l1q[q] += dpp_mov<0x114>(l1q[q]); l1q[q] += dpp_mov<0x118>(l1q[q]);
    }
    if ((lane & 15) >= 12) {
        int k = lane >> 4;
        int wk = (wave << 2) + k;
        #pragma unroll
        for (int q = 0; q < 4; ++q) {
            *(float4*)&sO[(wk)      * 64 + (q << 4) + (h << 2)] = *(const float4*)&O0[q << 2];
            *(float4*)&sO[(16 + wk) * 64 + (q << 4) + (h << 2)] = *(const float4*)&O1[q << 2];
        }
        if (h == 0) {
            #pragma unroll
            for (int q = 0; q < 4; ++q) {
                sL[(wk << 2) + q]      = l0q[q];
                sL[64 + (wk << 2) + q] = l1q[q];
            }
        }
    }
    __syncthreads();
    if (tid < 128) {
        int ii = tid >> 6, c = tid & 63;
        float o = 0.f, l = 0.f;
        #pragma unroll
        for (int wk = 0; wk < 16; ++wk) {
            o += sO[(ii * 16 + wk) * 64 + c];
            l += sL[ii * 64 + (wk << 2) + (c >> 4)];
        }
        int idx = (((p << 1) | ii) << 1) | js;
        Opar[(idx << 6) + c] = o;
        if ((c & 15) == 0) lpar[(idx << 2) + (c >> 4)] = l;
    }
}

__device__ __forceinline__ float combine_val(const float* __restrict__ Opar,
                                             const float* __restrict__ lpar,
                                             const float* __restrict__ bias,
                                             int r, int c) {
    int b = r >> 10, i = r & 1023;
    int p = (b << 9) | (i >> 1);
    int ii = i & 1;
    int base = ((p << 1) | ii) << 1;
    float o = Opar[(base << 6) + c] + Opar[((base + 1) << 6) + c];
    float l = lpar[(base << 2) + (c >> 4)] + lpar[((base + 1) << 2) + (c >> 4)];
    return o / l + bias[c];
}

// --- K1: mask tile + layer-1 dual-GEMM row, 2048 blocks -------------------
__global__ __launch_bounds__(256) void k_p1(const float* __restrict__ x,
                                            const float* __restrict__ emb,
                                            const float* __restrict__ Wl1,
                                            const float* __restrict__ Wr1,
                                            const float* __restrict__ att1,
                                            unsigned char* __restrict__ mask,
                                            float* __restrict__ xl,
                                            float* __restrict__ xr,
                                            float* __restrict__ alE) {
    __shared__ float sm[32 * 65 + 16 * 65];
    __shared__ float hrow[64];
    int bid = blockIdx.x;
    if (threadIdx.x < 64) hrow[threadIdx.x] = x[bid * 64 + threadIdx.x];
    mask_tile(emb, mask, bid, sm);
    __syncthreads();
    gemm_row(Wl1, Wr1, att1, hrow, xl, xr, alE, bid);
}

// --- K2/K4: attention partials, task = blockIdx ---------------------------
__global__ __launch_bounds__(256) void k_attn_f(const float* __restrict__ xl,
                                                const float* __restrict__ xr,
                                                const float* __restrict__ att,
                                                const float* __restrict__ alE,
                                                const unsigned char* __restrict__ mask,
                                                float* __restrict__ Opar,
                                                float* __restrict__ lpar) {
    __shared__ float sm[2176];
    attn_partial(xl, xr, att, alE, mask, Opar, lpar, blockIdx.x, sm);
}

// --- K3: combine layer-1 (+relu) fused into layer-2 dual-GEMM row ---------
__global__ __launch_bounds__(256) void k_comb_gemm(const float* __restrict__ Opar,
                                                   const float* __restrict__ lpar,
                                                   const float* __restrict__ b1,
                                                   const float* __restrict__ Wl2,
                                                   const float* __restrict__ Wr2,
                                                   const float* __restrict__ att2,
                                                   float* __restrict__ xl,
                                                   float* __restrict__ xr,
                                                   float* __restrict__ alE) {
    __shared__ float hrow[64];
    int bid = blockIdx.x;
    if (threadIdx.x < 64)
        hrow[threadIdx.x] = fmaxf(combine_val(Opar, lpar, b1, bid, threadIdx.x), 0.f);
    __syncthreads();
    gemm_row(Wl2, Wr2, att2, hrow, xl, xr, alE, bid);
}

// --- K5: combine layer-2 -> out -------------------------------------------
__global__ __launch_bounds__(64) void k_comb_out(const float* __restrict__ Opar,
                                                 const float* __restrict__ lpar,
                                                 const float* __restrict__ b2,
                                                 float* __restrict__ out) {
    out[blockIdx.x * 64 + threadIdx.x] =
        combine_val(Opar, lpar, b2, blockIdx.x, threadIdx.x);
}

extern "C" void kernel_launch(void* const* d_in, const int* in_sizes, int n_in,
                              void* d_out, int out_size, void* d_ws, size_t ws_size,
                              hipStream_t stream) {
    const float* x    = (const float*)d_in[0];
    const float* emb  = (const float*)d_in[1];
    const float* Wl1  = (const float*)d_in[2];
    const float* Wr1  = (const float*)d_in[3];
    const float* att1 = (const float*)d_in[4];
    const float* b1   = (const float*)d_in[5];
    const float* Wl2  = (const float*)d_in[6];
    const float* Wr2  = (const float*)d_in[7];
    const float* att2 = (const float*)d_in[8];
    const float* b2   = (const float*)d_in[9];
    float* out = (float*)d_out;

    unsigned char* mask = (unsigned char*)d_ws;        // 1 MB
    float* xl   = (float*)(mask + NN * NN);            // 512 KB
    float* xr   = xl + 2 * NN * 64;                    // 512 KB
    float* alE  = xr + 2 * NN * 64;                    // 32 KB
    float* Opar = alE + 2 * NN * 4;                    // 1 MB  [ipair|ii|js][64]
    float* lpar = Opar + 1024 * 2 * 2 * 64;            // 64 KB [ipair|ii|js][4]

    k_p1<<<2048, 256, 0, stream>>>(x, emb, Wl1, Wr1, att1, mask, xl, xr, alE);
    k_attn_f<<<2048, 256, 0, stream>>>(xl, xr, att1, alE, mask, Opar, lpar);
    k_comb_gemm<<<2048, 256, 0, stream>>>(Opar, lpar, b1, Wl2, Wr2, att2, xl, xr, alE);
    k_attn_f<<<2048, 256, 0, stream>>>(xl, xr, att2, alE, mask, Opar, lpar);
    k_comb_out<<<2048, 64, 0, stream>>>(Opar, lpar, b2, out);
}

// Round 10
// 147.745 us; speedup vs baseline: 1.2676x; 1.0100x over previous
//
#include <hip/hip_runtime.h>
#include <math.h>

#define NN 1024
#define LOG2E 1.4426950408889634f

template <int CTRL>
__device__ __forceinline__ float dpp_mov(float x) {
    int xi = __builtin_bit_cast(int, x);
    int r = __builtin_amdgcn_update_dpp(0, xi, CTRL, 0xF, 0xF, true);
    return __builtin_bit_cast(float, r);
}
__device__ __forceinline__ float dpp_rowsum16(float t) {
    t += dpp_mov<0x111>(t);
    t += dpp_mov<0x112>(t);
    t += dpp_mov<0x114>(t);
    t += dpp_mov<0x118>(t);
    return t;
}
__device__ __forceinline__ float quad_sum4(float t) {
    t += dpp_mov<0xB1>(t);   // quad_perm [1,0,3,2]
    t += dpp_mov<0x4E>(t);   // quad_perm [2,3,0,1]
    return t;
}

// --- one 32(i) x 16(j) adjacency tile per task ----------------------------
// (emb_i.emb_j != 0) <=> (ne_i.ne_j != 0) since norms are positive finite.
__device__ void mask_tile(const float* __restrict__ emb,
                          unsigned char* __restrict__ mask, int task, float* sm) {
    float* As = sm;             // 32*65
    float* Bs = sm + 32 * 65;   // 16*65
    int tid = threadIdx.x;
    int ib = (task & 31) << 5;
    int jb = (task >> 5) << 4;
    #pragma unroll
    for (int r = 0; r < 2; ++r) {
        int q = tid + (r << 8);
        int row = q >> 4, c4 = (q & 15) << 2;
        float4 a = *(const float4*)&emb[(ib + row) * 64 + c4];
        As[row * 65 + c4 + 0] = a.x; As[row * 65 + c4 + 1] = a.y;
        As[row * 65 + c4 + 2] = a.z; As[row * 65 + c4 + 3] = a.w;
    }
    {
        int row = tid >> 4, c4 = (tid & 15) << 2;
        float4 b = *(const float4*)&emb[(jb + row) * 64 + c4];
        Bs[row * 65 + c4 + 0] = b.x; Bs[row * 65 + c4 + 1] = b.y;
        Bs[row * 65 + c4 + 2] = b.z; Bs[row * 65 + c4 + 3] = b.w;
    }
    __syncthreads();
    int i1 = tid >> 4, j = tid & 15;
    float acc1 = 0.f, acc2 = 0.f;
    #pragma unroll 8
    for (int k = 0; k < 64; ++k) {
        float bv = Bs[j * 65 + k];
        acc1 = fmaf(As[i1 * 65 + k], bv, acc1);
        acc2 = fmaf(As[(i1 + 16) * 65 + k], bv, acc2);
    }
    int gi1 = ib + i1, gi2 = ib + i1 + 16, gj = jb + j;
    mask[gi1 * NN + gj] = (acc1 != 0.f || gi1 == gj) ? 1 : 0;
    mask[gi2 * NN + gj] = (acc2 != 0.f || gi2 == gj) ? 1 : 0;
}

// --- Attention core: TI=2 rows, full j range, quad-cooperative ------------
// lane = 4*jl + h; quad shares row j = wave*256 + jl*16 + s (16 steps).
// e' = quadsum(sum at'|xr+xv|) + arE + alE[j]; pe = exp2(e') (e bounded).
// Returns per-thread (o, l) for tid<128: ii = tid>>6, c = tid&63.
__device__ void attn_core(const float* __restrict__ xl, const float* __restrict__ xr,
                          const float* __restrict__ att, const float* __restrict__ alE,
                          const unsigned char* __restrict__ mask,
                          int p, float* sm, float& oOut, float& lOut) {
    float* sO = sm;          // [ii][16 wk][64]  = 2048 floats
    float* sL = sm + 2048;   // [ii][16 wk][4 q] = 128 floats
    int tid = threadIdx.x;
    int wave = tid >> 6, lane = tid & 63;
    int h = lane & 3, jl = lane >> 2;
    int b  = p >> 9;
    int i0 = (p & 511) << 1;
    int j0 = (wave << 8) + (jl << 4);

    const float* xlb = xl + (b << 16);
    float at[16], xr0f[16], xr1f[16];
    {
        const float* ap = att + (h << 2);
        const float* r0 = xr + (((b << 10) + i0) << 6) + (h << 2);
        const float* r1 = r0 + 64;
        #pragma unroll
        for (int q = 0; q < 4; ++q) {
            *(float4*)&at[q << 2]   = *(const float4*)(ap + (q << 4));
            *(float4*)&xr0f[q << 2] = *(const float4*)(r0 + (q << 4));
            *(float4*)&xr1f[q << 2] = *(const float4*)(r1 + (q << 4));
        }
        #pragma unroll
        for (int pp = 0; pp < 16; ++pp) at[pp] *= 0.4f * LOG2E;
    }
    float ar0q[4], ar1q[4];
    #pragma unroll
    for (int q = 0; q < 4; ++q) {
        float p0 = 0.f, p1 = 0.f;
        #pragma unroll
        for (int rr = 0; rr < 4; ++rr) {
            p0 = fmaf(at[(q << 2) + rr], xr0f[(q << 2) + rr], p0);
            p1 = fmaf(at[(q << 2) + rr], xr1f[(q << 2) + rr], p1);
        }
        ar0q[q] = 1.5f * quad_sum4(p0);
        ar1q[q] = 1.5f * quad_sum4(p1);
    }
    unsigned mb0 = 0, mb1 = 0;
    {
        const unsigned* m0p = (const unsigned*)(mask + i0 * NN + j0);
        const unsigned* m1p = (const unsigned*)(mask + (i0 + 1) * NN + j0);
        #pragma unroll
        for (int q = 0; q < 4; ++q) {
            unsigned w0 = m0p[q], w1 = m1p[q];
            mb0 |= ((((w0 >> 0) & 1) | ((w0 >> 7) & 2) | ((w0 >> 14) & 4) | ((w0 >> 21) & 8)) << (q << 2));
            mb1 |= ((((w1 >> 0) & 1) | ((w1 >> 7) & 2) | ((w1 >> 14) & 4) | ((w1 >> 21) & 8)) << (q << 2));
        }
    }
    float O0[16], O1[16], l0q[4] = {0,0,0,0}, l1q[4] = {0,0,0,0};
    #pragma unroll
    for (int pp = 0; pp < 16; ++pp) { O0[pp] = 0.f; O1[pp] = 0.f; }
    const float* xrow = xlb + (j0 << 6) + (h << 2);
    const float* alp  = alE + (b << 12) + (j0 << 2);
    #pragma unroll 2
    for (int s = 0; s < 16; ++s) {
        const float* rp = xrow + (s << 6);
        float xv[16];
        *(float4*)&xv[0]  = *(const float4*)(rp);
        *(float4*)&xv[4]  = *(const float4*)(rp + 16);
        *(float4*)&xv[8]  = *(const float4*)(rp + 32);
        *(float4*)&xv[12] = *(const float4*)(rp + 48);
        float alr[4];
        *(float4*)alr = *(const float4*)(alp + (s << 2));
        bool m0 = (mb0 >> s) & 1, m1 = (mb1 >> s) & 1;
        #pragma unroll
        for (int q = 0; q < 4; ++q) {
            float p0 = 0.f, p1 = 0.f;
            #pragma unroll
            for (int rr = 0; rr < 4; ++rr) {
                float xvv = xv[(q << 2) + rr];
                float a = at[(q << 2) + rr];
                p0 = fmaf(a, __builtin_fabsf(xr0f[(q << 2) + rr] + xvv), p0);
                p1 = fmaf(a, __builtin_fabsf(xr1f[(q << 2) + rr] + xvv), p1);
            }
            float e0 = quad_sum4(p0) + (ar0q[q] + alr[q]);
            float e1 = quad_sum4(p1) + (ar1q[q] + alr[q]);
            float pe0 = m0 ? __builtin_amdgcn_exp2f(e0) : 0.f;
            float pe1 = m1 ? __builtin_amdgcn_exp2f(e1) : 0.f;
            l0q[q] += pe0; l1q[q] += pe1;
            #pragma unroll
            for (int rr = 0; rr < 4; ++rr) {
                float xvv = xv[(q << 2) + rr];
                O0[(q << 2) + rr] = fmaf(pe0, xvv, O0[(q << 2) + rr]);
                O1[(q << 2) + rr] = fmaf(pe1, xvv, O1[(q << 2) + rr]);
            }
        }
    }
    #pragma unroll
    for (int pp = 0; pp < 16; ++pp) {
        O0[pp] += dpp_mov<0x114>(O0[pp]); O0[pp] += dpp_mov<0x118>(O0[pp]);
        O1[pp] += dpp_mov<0x114>(O1[pp]); O1[pp] += dpp_mov<0x118>(O1[pp]);
    }
    #pragma unroll
    for (int q = 0; q < 4; ++q) {
        l0q[q] += dpp_mov<0x114>(l0q[q]); l0q[q] += dpp_mov<0x118>(l0q[q]);
        l1q[q] += dpp_mov<0x114>(l1q[q]); l1q[q] += dpp_mov<0x118>(l1q[q]);
    }
    if ((lane & 15) >= 12) {
        int k = lane >> 4;
        int wk = (wave << 2) + k;
        #pragma unroll
        for (int q = 0; q < 4; ++q) {
            *(float4*)&sO[(wk)      * 64 + (q << 4) + (h << 2)] = *(const float4*)&O0[q << 2];
            *(float4*)&sO[(16 + wk) * 64 + (q << 4) + (h << 2)] = *(const float4*)&O1[q << 2];
        }
        if (h == 0) {
            #pragma unroll
            for (int q = 0; q < 4; ++q) {
                sL[(wk << 2) + q]      = l0q[q];
                sL[64 + (wk << 2) + q] = l1q[q];
            }
        }
    }
    __syncthreads();
    if (tid < 128) {
        int ii = tid >> 6, c = tid & 63;
        float o = 0.f, l = 0.f;
        #pragma unroll
        for (int wk = 0; wk < 16; ++wk) {
            o += sO[(ii * 16 + wk) * 64 + c];
            l += sL[ii * 64 + (wk << 2) + (c >> 4)];
        }
        oOut = o; lOut = l;
    }
}

// --- K1: mask tile + layer-1 dual-GEMM row, 2048 blocks -------------------
__global__ __launch_bounds__(256) void k_p1(const float* __restrict__ x,
                                            const float* __restrict__ emb,
                                            const float* __restrict__ Wl1,
                                            const float* __restrict__ Wr1,
                                            const float* __restrict__ att1,
                                            unsigned char* __restrict__ mask,
                                            float* __restrict__ xl,
                                            float* __restrict__ xr,
                                            float* __restrict__ alE) {
    __shared__ float sm[32 * 65 + 16 * 65];
    __shared__ float hrow[64];
    int bid = blockIdx.x;
    int tid = threadIdx.x;
    if (tid < 64) hrow[tid] = x[bid * 64 + tid];
    mask_tile(emb, mask, bid, sm);
    __syncthreads();
    if (tid < 64) {
        int c = tid;
        float accl = 0.f, accr = 0.f;
        #pragma unroll 8
        for (int p = 0; p < 64; ++p) {
            float a = hrow[p];
            accl = fmaf(a, Wl1[p * 64 + c], accl);
            accr = fmaf(a, Wr1[p * 64 + c], accr);
        }
        xl[bid * 64 + c] = accl;
        xr[bid * 64 + c] = accr;
        float t = dpp_rowsum16(accl * att1[c]);
        if ((c & 15) == 15) alE[(bid << 2) | (c >> 4)] = 0.6f * LOG2E * t;
    }
}

// --- K2: layer-1 attention + epilogue + fused layer-2 dual-GEMM -----------
__global__ __launch_bounds__(256, 4) void k_attn_gemm(
    const float* __restrict__ xl1, const float* __restrict__ xr1,
    const float* __restrict__ att1, const float* __restrict__ alE1,
    const unsigned char* __restrict__ mask, const float* __restrict__ b1,
    const float* __restrict__ Wl2, const float* __restrict__ Wr2,
    const float* __restrict__ att2,
    float* __restrict__ xl2, float* __restrict__ xr2, float* __restrict__ alE2)
{
    __shared__ float sm[2176];
    __shared__ float hrow[2][64];
    float o = 0.f, l = 1.f;
    attn_core(xl1, xr1, att1, alE1, mask, blockIdx.x, sm, o, l);
    int tid = threadIdx.x;
    if (tid < 128) {
        int ii = tid >> 6, c = tid & 63;
        hrow[ii][c] = fmaxf(o / l + b1[c], 0.f);   // layer-1 output row (relu)
    }
    __syncthreads();
    if (tid < 128) {
        int ii = tid >> 6, c = tid & 63;
        int g = ((blockIdx.x >> 9) << 10) + ((blockIdx.x & 511) << 1) + ii;
        const float* hr = hrow[ii];
        float accl = 0.f, accr = 0.f;
        #pragma unroll 8
        for (int p = 0; p < 64; ++p) {
            float a = hr[p];
            accl = fmaf(a, Wl2[p * 64 + c], accl);
            accr = fmaf(a, Wr2[p * 64 + c], accr);
        }
        xl2[g * 64 + c] = accl;
        xr2[g * 64 + c] = accr;
        float t = dpp_rowsum16(accl * att2[c]);
        if ((c & 15) == 15) alE2[(g << 2) | (c >> 4)] = 0.6f * LOG2E * t;
    }
}

// --- K3: layer-2 attention + epilogue -> out ------------------------------
__global__ __launch_bounds__(256, 4) void k_attn_out(
    const float* __restrict__ xl2, const float* __restrict__ xr2,
    const float* __restrict__ att2, const float* __restrict__ alE2,
    const unsigned char* __restrict__ mask, const float* __restrict__ b2,
    float* __restrict__ out)
{
    __shared__ float sm[2176];
    float o = 0.f, l = 1.f;
    attn_core(xl2, xr2, att2, alE2, mask, blockIdx.x, sm, o, l);
    int tid = threadIdx.x;
    if (tid < 128) {
        int ii = tid >> 6, c = tid & 63;
        int g = ((blockIdx.x >> 9) << 10) + ((blockIdx.x & 511) << 1) + ii;
        out[g * 64 + c] = o / l + b2[c];
    }
}

extern "C" void kernel_launch(void* const* d_in, const int* in_sizes, int n_in,
                              void* d_out, int out_size, void* d_ws, size_t ws_size,
                              hipStream_t stream) {
    const float* x    = (const float*)d_in[0];
    const float* emb  = (const float*)d_in[1];
    const float* Wl1  = (const float*)d_in[2];
    const float* Wr1  = (const float*)d_in[3];
    const float* att1 = (const float*)d_in[4];
    const float* b1   = (const float*)d_in[5];
    const float* Wl2  = (const float*)d_in[6];
    const float* Wr2  = (const float*)d_in[7];
    const float* att2 = (const float*)d_in[8];
    const float* b2   = (const float*)d_in[9];
    float* out = (float*)d_out;

    unsigned char* mask = (unsigned char*)d_ws;        // 1 MB
    float* xl1  = (float*)(mask + NN * NN);            // 512 KB
    float* xr1  = xl1 + 2 * NN * 64;                   // 512 KB
    float* alE1 = xr1 + 2 * NN * 64;                   // 32 KB
    float* xl2  = alE1 + 2 * NN * 4;                   // 512 KB
    float* xr2  = xl2 + 2 * NN * 64;                   // 512 KB
    float* alE2 = xr2 + 2 * NN * 64;                   // 32 KB

    k_p1<<<2048, 256, 0, stream>>>(x, emb, Wl1, Wr1, att1, mask, xl1, xr1, alE1);
    k_attn_gemm<<<1024, 256, 0, stream>>>(xl1, xr1, att1, alE1, mask, b1,
                                          Wl2, Wr2, att2, xl2, xr2, alE2);
    k_attn_out<<<1024, 256, 0, stream>>>(xl2, xr2, att2, alE2, mask, b2, out);
}